// Round 11
// baseline (211.490 us; speedup 1.0000x reference)
//
#include <hip/hip_runtime.h>
#include <math.h>

// Problem constants
#define LQ 1024
#define EQ 512
#define BQ 32
#define MQ 64

static constexpr int BCHUNK = LQ * EQ;   // 524288 floats per b-slice of d_out
// d_out overlay (per b-slice of 524288 floats), phase by phase:
//  k_trig:   Tm bf16 A-frags in slice0 floats [0, 131072)
//  k_dft4:   reads q + Tm-frags; writes SPLITX bf16 arrays 0..3 (sx_ptr) in
//            slices z=0..7 at [z][262144, 524288)  (disjoint from Tm-frags)
//  k_modes9: Opart[hs][c][i] hs=0..3 at b*BCHUNK + hs*65536  [0,262144)
//  k_inv3:   y[l][i] overwrites slice. Each block reads ONLY its own i-columns
//            of the 4 partials (staged to LDS before any write -> WAR-safe).

typedef short short8 __attribute__((ext_vector_type(8)));
typedef float f32x4 __attribute__((ext_vector_type(4)));
typedef unsigned short ushort_t;

union FragI { int i[4]; int4 v; short8 s; };

// async global->LDS, 16B per lane; dest must be wave-uniform base (+lane*16 HW)
__device__ __forceinline__ void gload16(const float* g, float* l) {
    __builtin_amdgcn_global_load_lds(
        (const __attribute__((address_space(1))) void*)g,
        (__attribute__((address_space(3))) void*)l, 16, 0, 0);
}

// SPLITX: 4 bf16 arrays [m(64)][hblk(16)][b(32)][hh(32)], arr: 0=xrHi 1=xrLo
// 2=xiHi 3=xiLo. Flat bf16 index G = arr*2^20 + m*16384 + (h/32)*1024 + b*32
// + (h%32), mapped into 1MB-float zones: z = G>>19 at slice z offset 262144.
__device__ inline char* sx_ptr(float* dout, int arr, int m, int b, int h) {
    unsigned G = ((unsigned)arr << 20) + ((unsigned)m << 14) +
                 ((unsigned)(h >> 5) << 10) + ((unsigned)b << 5) + (unsigned)(h & 31);
    unsigned z = G >> 19, w = G & 524287u;
    return (char*)(dout + (size_t)z * BCHUNK + 262144) + (size_t)w * 2;
}

// split two fp32 into packed bf16 pairs (truncation; lo captures the residual)
__device__ inline void split2(float a, float b, unsigned& hi, unsigned& lo) {
    unsigned ua = __float_as_uint(a), ub = __float_as_uint(b);
    unsigned ha = ua & 0xFFFF0000u, hb = ub & 0xFFFF0000u;
    hi = (ua >> 16) | hb;
    float la = a - __uint_as_float(ha);
    float lb = b - __uint_as_float(hb);
    lo = (__float_as_uint(la) >> 16) | (__float_as_uint(lb) & 0xFFFF0000u);
}

__device__ inline void split1(float x, ushort_t& hi, ushort_t& lo) {
    unsigned u = __float_as_uint(x);
    hi = (ushort_t)(u >> 16);
    float r = x - __uint_as_float(u & 0xFFFF0000u);
    lo = (ushort_t)(__float_as_uint(r) >> 16);
}

// ---------------- kernel 0: trig tables (unchanged) ----------------
__global__ __launch_bounds__(256) void k_trig(unsigned* __restrict__ BFhi,
                                              unsigned* __restrict__ BFlo,
                                              float* __restrict__ dout) {
    int idx = blockIdx.x * 256 + threadIdx.x;   // 0..65535 = l*64+m
    int l = idx >> 6, m = idx & 63;
    int tt = (l * m) & (LQ - 1);
    float ang = (float)tt * 6.135923151542565e-03f;  // 2*pi/1024
    float s, c;
    sincosf(ang, &s, &c);
    float coef = (m == 0 ? 1.0f : 2.0f) * (1.0f / (float)LQ);
    float b0 = coef * c;
    float b1 = (m == 0) ? 0.0f : (-2.0f / (float)LQ) * s;
    unsigned hi, lo;
    split2(b0, b1, hi, lo);
    {
        int lt = l >> 4, kb = m >> 4, kgb = (m & 15) >> 2;
        int lane = kgb * 16 + (l & 15);
        int u = lt * 1024 + kb * 256 + lane * 4 + (m & 3);
        BFhi[u] = hi;
        BFlo[u] = lo;
    }
    ushort_t* THs = (ushort_t*)dout;
    ushort_t* TLs = (ushort_t*)(dout + 65536);
    int ks = l >> 5, kg = (l >> 3) & 3, j = l & 7;
    int mt = m >> 3;
    int lane0 = kg * 16 + 2 * (m & 7);
    ushort_t ch, cl, sh, sl;
    split1(c, ch, cl);
    split1(-s, sh, sl);
    int u0 = ((ks * 8 + mt) * 64 + lane0) * 8 + j;
    THs[u0] = ch;  TLs[u0] = cl;
    THs[u0 + 8] = sh;  TLs[u0 + 8] = sl;
}

#define MM(A, B, C) C = __builtin_amdgcn_mfma_f32_16x16x32_bf16(A, B, C, 0, 0, 0)

// ---------------- kernel 1: truncated DFT via MFMA (unchanged round-9) -----
__global__ __launch_bounds__(512, 4) void k_dft4(const float* __restrict__ q,
                                                 float* __restrict__ dout) {
    __shared__ float qs[2 * 2048];      // 16KB: [buf][lp 64][h 32]
    const int t    = threadIdx.x;
    const int wave = t >> 6;
    const int lane = t & 63;
    const int a    = wave & 3;
    const int ht   = wave >> 2;
    const int b    = blockIdx.x >> 4;
    const int hg   = blockIdx.x & 15;
    const int hbase = hg * 32;
    const int col  = lane & 15;
    const int kg   = lane >> 4;
    const float* qb = q + (size_t)b * BCHUNK;
    const int4* TH4 = (const int4*)dout;
    const int4* TL4 = (const int4*)(dout + 65536);

    f32x4 acc[2] = {{0.f, 0.f, 0.f, 0.f}, {0.f, 0.f, 0.f, 0.f}};
    const int lp = wave * 8 + (lane >> 3);     // slot row for gload src
    const int hq = 4 * (lane & 7);

    gload16(qb + (size_t)lp * EQ + hbase + hq, &qs[wave * 256]);

    int cur = 0;
    for (int cc = 0; cc < 16; ++cc) {
        __syncthreads();                        // q(cc) ready in buf[cur]
        FragI ah[2][2], al[2][2];
#pragma unroll
        for (int ksl = 0; ksl < 2; ++ksl)
#pragma unroll
            for (int ti = 0; ti < 2; ++ti) {
                int idx = ((cc * 2 + ksl) * 8 + 2 * a + ti) * 64 + lane;
                ah[ksl][ti].v = TH4[idx];
                al[ksl][ti].v = TL4[idx];
            }
        if (cc < 15)
            gload16(qb + (size_t)((cc + 1) * 64 + lp) * EQ + hbase + hq,
                    &qs[(cur ^ 1) * 2048 + wave * 256]);
#pragma unroll
        for (int ksl = 0; ksl < 2; ++ksl) {
            float v[8];
#pragma unroll
            for (int j = 0; j < 8; ++j)
                v[j] = qs[cur * 2048 + (ksl * 32 + kg * 8 + j) * 32 + ht * 16 + col];
            FragI bhiF, bloF;
#pragma unroll
            for (int k2 = 0; k2 < 4; ++k2) {
                unsigned h_, l_;
                split2(v[2 * k2], v[2 * k2 + 1], h_, l_);
                bhiF.i[k2] = (int)h_;
                bloF.i[k2] = (int)l_;
            }
#pragma unroll
            for (int ti = 0; ti < 2; ++ti) {
                MM(ah[ksl][ti].s, bhiF.s, acc[ti]);
                MM(ah[ksl][ti].s, bloF.s, acc[ti]);
                MM(al[ksl][ti].s, bhiF.s, acc[ti]);
            }
        }
        cur ^= 1;
    }
    const int h = hbase + ht * 16 + col;
#pragma unroll
    for (int ti = 0; ti < 2; ++ti) {
        int mt = 2 * a + ti;
        int mA = mt * 8 + kg * 2;
#pragma unroll
        for (int mi = 0; mi < 2; ++mi) {
            float xr = acc[ti][2 * mi];
            float xi = acc[ti][2 * mi + 1];
            ushort_t rh, rl, ih_, il_;
            split1(xr, rh, rl);
            split1(xi, ih_, il_);
            int m = mA + mi;
            *(ushort_t*)sx_ptr(dout, 0, m, b, h) = rh;
            *(ushort_t*)sx_ptr(dout, 1, m, b, h) = rl;
            *(ushort_t*)sx_ptr(dout, 2, m, b, h) = ih_;
            *(ushort_t*)sx_ptr(dout, 3, m, b, h) = il_;
        }
    }
}

// ---------------- kernel 2: per-mode complex GEMM, v10 ----------------
// Opart[hs][b][2m+ri][i] = sum_{h in hs quarter} X[b][h][m] * W[h][i][m]
// grid 512 = hs(4) x mg(16: 4 m) x it(8: 64 i). block 512 = 8 waves.
// KEY CHANGE vs round 10: ALL FOUR X groups for chunk kk are loaded in the
// PREVIOUS iteration, before its end barrier. The chunk body is then:
// READW (lgkm only) -> barrier -> STAGE(kk+1) -> 48 pure-register MFMA
// (zero vmcnt waits -> W prefetch never force-drained) -> LDX X(kk+1) ->
// barrier (single vmcnt(0) drain/chunk, overlapped by the compute window).
__global__ __launch_bounds__(512, 4) void k_modes9(const float* __restrict__ wreal,
                                                   const float* __restrict__ wimag,
                                                   float* __restrict__ dout) {
    __shared__ float Wlds[16384];        // 64KB
    const int t    = threadIdx.x;
    const int wave = t >> 6;
    const int lane = t & 63;
    const int isub = wave >> 1;          // 0..3
    const int mw   = wave & 1;           // 0..1
    const int blk  = blockIdx.x;
    const int hs   = blk >> 7;           // 0..3
    const int mg   = (blk >> 3) & 15;    // 0..15
    const int it   = blk & 7;            // 0..7  (same XCD for all 16 mg)
    const int i0   = it * 64;
    const int m0   = mg * 4;
    const int col  = lane & 15;
    const int kg   = lane >> 4;
    const int hbase = hs * 128;

    const char* xp0 = sx_ptr(dout, 0, m0 + 2 * mw, col, hbase + kg * 8);

    f32x4 zero4 = {0.f, 0.f, 0.f, 0.f};
    f32x4 acc[2][2][2];                  // [mi][part][nt]
#pragma unroll
    for (int a = 0; a < 2; ++a)
#pragma unroll
        for (int bq = 0; bq < 2; ++bq)
#pragma unroll
            for (int c = 0; c < 2; ++c) acc[a][bq][c] = zero4;

    FragI xA[4], xB[4], xC[4], xD[4];    // X for groups (mi,nt)=(0,0)(0,1)(1,0)(1,1)
    short8 aW[2][2][2];                  // [mi][part][prec]

#define STAGE(KK)                                                             \
    {                                                                         \
        _Pragma("unroll")                                                     \
        for (int r = 0; r < 8; ++r) {                                         \
            const int W64_ = r * 8 + wave;                                    \
            const int part_ = W64_ >> 5;                                      \
            const int h_ = W64_ & 31;                                         \
            const float* src_ = (part_ ? wimag : wreal) +                     \
                (size_t)(hbase + (KK) * 32 + h_) * 32768 +                    \
                (size_t)(i0 + lane) * 64 + m0;                                \
            gload16(src_, &Wlds[W64_ * 256]);                                 \
        }                                                                     \
    }

#define LDX(BUF, MI, NT, KK)                                                  \
    {                                                                         \
        const char* xpm_ = xp0 + (size_t)(MI) * 32768 +                       \
                           (size_t)(KK) * 2048 + (size_t)(NT) * 1024;         \
        BUF[0].v = *(const int4*)(xpm_);                                      \
        BUF[1].v = *(const int4*)(xpm_ + 4194304);                            \
        BUF[2].v = *(const int4*)(xpm_ + 2 * 4194304);                        \
        BUF[3].v = *(const int4*)(xpm_ + 3 * 4194304);                        \
    }

#define MMG(MI, NT, BUF)                                                      \
    {                                                                         \
        FragI th_, tl_, nh_, nl_;                                             \
        th_.s = aW[MI][1][0]; tl_.s = aW[MI][1][1];                           \
        _Pragma("unroll")                                                     \
        for (int k2 = 0; k2 < 4; ++k2) {                                      \
            nh_.i[k2] = th_.i[k2] ^ 0x80008000;                               \
            nl_.i[k2] = tl_.i[k2] ^ 0x80008000;                               \
        }                                                                     \
        MM(aW[MI][0][0], BUF[0].s, acc[MI][0][NT]);                           \
        MM(aW[MI][0][0], BUF[1].s, acc[MI][0][NT]);                           \
        MM(aW[MI][0][1], BUF[0].s, acc[MI][0][NT]);                           \
        MM(nh_.s,        BUF[2].s, acc[MI][0][NT]);                           \
        MM(nh_.s,        BUF[3].s, acc[MI][0][NT]);                           \
        MM(nl_.s,        BUF[2].s, acc[MI][0][NT]);                           \
        MM(aW[MI][0][0], BUF[2].s, acc[MI][1][NT]);                           \
        MM(aW[MI][0][0], BUF[3].s, acc[MI][1][NT]);                           \
        MM(aW[MI][0][1], BUF[2].s, acc[MI][1][NT]);                           \
        MM(aW[MI][1][0], BUF[0].s, acc[MI][1][NT]);                           \
        MM(aW[MI][1][0], BUF[1].s, acc[MI][1][NT]);                           \
        MM(aW[MI][1][1], BUF[0].s, acc[MI][1][NT]);                           \
    }

    // prologue: W chunk 0 + all X groups for chunk 0, one drain
    STAGE(0);
    LDX(xA, 0, 0, 0);
    LDX(xB, 0, 1, 0);
    LDX(xC, 1, 0, 0);
    LDX(xD, 1, 1, 0);
    __syncthreads();                     // chunk 0 in Wlds, X(0) in regs
    for (int kk = 0; kk < 4; ++kk) {
        // READW: Wlds -> aW registers (LDS reads only, lgkmcnt)
#pragma unroll
        for (int part = 0; part < 2; ++part) {
            float2 v2[8];
#pragma unroll
            for (int j = 0; j < 8; ++j)
                v2[j] = *(const float2*)&Wlds[(part * 32 + kg * 8 + j) * 256 +
                                              (isub * 16 + col) * 4 + 2 * mw];
#pragma unroll
            for (int mi = 0; mi < 2; ++mi) {
                FragI hiF, loF;
#pragma unroll
                for (int k2 = 0; k2 < 4; ++k2) {
                    float a_ = mi ? v2[2 * k2].y : v2[2 * k2].x;
                    float b_ = mi ? v2[2 * k2 + 1].y : v2[2 * k2 + 1].x;
                    unsigned h_, l_;
                    split2(a_, b_, h_, l_);
                    hiF.i[k2] = (int)h_;
                    loF.i[k2] = (int)l_;
                }
                aW[mi][part][0] = hiF.s;
                aW[mi][part][1] = loF.s;
            }
        }
        __syncthreads();                 // all waves done reading Wlds(kk)
        if (kk < 3) STAGE(kk + 1);       // W prefetch: stays in flight through
                                         // the entire MFMA phase (no waits below)
        MMG(0, 0, xA);                   // pure-register compute
        MMG(0, 1, xB);
        MMG(1, 0, xC);
        MMG(1, 1, xD);
        if (kk < 3) {                    // X for next chunk; consumed only
            LDX(xA, 0, 0, kk + 1);       // after the barrier's vmcnt(0) drain
            LDX(xB, 0, 1, kk + 1);
            LDX(xC, 1, 0, kk + 1);
            LDX(xD, 1, 1, kk + 1);
        }
        __syncthreads();                 // single drain: Wlds(kk+1) + X ready
    }
#undef STAGE
#undef LDX
#undef MMG
    // epilogue: D row = i = i0 + isub*16 + kg*4 + reg (contig float4), col = b
#pragma unroll
    for (int mi = 0; mi < 2; ++mi)
#pragma unroll
        for (int part = 0; part < 2; ++part)
#pragma unroll
            for (int nt = 0; nt < 2; ++nt) {
                int bb = nt * 16 + col;
                int c = 2 * (m0 + 2 * mw + mi) + part;
                f32x4 vv = acc[mi][part][nt];
                float4 o = make_float4(vv.x, vv.y, vv.z, vv.w);
                *(float4*)&dout[(size_t)bb * BCHUNK + (size_t)hs * 65536 +
                                (size_t)c * EQ + i0 + isub * 16 + kg * 4] = o;
            }
}

// ---------------- kernel 3: truncated irfft via MFMA (unchanged) ----------
__global__ __launch_bounds__(256) void k_inv3(const unsigned* __restrict__ BFhi,
                                              const unsigned* __restrict__ BFlo,
                                              float* __restrict__ dout) {
    __shared__ unsigned Bf[4096];   // [hilo(2)][nt(2)][kb(4)][lane(64)][4] 16KB
    const int t    = threadIdx.x;
    const int wave = t >> 6;
    const int lane = t & 63;
    const int b    = blockIdx.x >> 4;
    const int it   = blockIdx.x & 15;
    const int i0   = it * 32;
    float* base = dout + (size_t)b * BCHUNK;

#pragma unroll
    for (int r = 0; r < 8; ++r) {
        int idx = r * 256 + t;               // 2048 = 64 c-pairs x 32 i
        int il = idx & 31, cp = idx >> 5;
        int c0 = 2 * cp;
        const float* p0 = base + (size_t)c0 * EQ + i0 + il;
        float s0 = p0[0] + p0[65536] + p0[2 * 65536] + p0[3 * 65536];
        const float* p1 = p0 + EQ;
        float s1 = p1[0] + p1[65536] + p1[2 * 65536] + p1[3 * 65536];
        unsigned hi, lo;
        split2(s0, s1, hi, lo);
        int nt = il >> 4, i_loc = il & 15;
        int kb = c0 >> 5, kg = (c0 & 31) >> 3, jp = (c0 & 7) >> 1;
        int u = (nt * 4 + kb) * 256 + (kg * 16 + i_loc) * 4 + jp;
        Bf[u] = hi;
        Bf[2048 + u] = lo;
    }
    __syncthreads();
    FragI bh[2][4], bl[2][4];
#pragma unroll
    for (int nt = 0; nt < 2; ++nt)
#pragma unroll
        for (int kb = 0; kb < 4; ++kb) {
            bh[nt][kb].v = *(const int4*)&Bf[(nt * 4 + kb) * 256 + lane * 4];
            bl[nt][kb].v = *(const int4*)&Bf[2048 + (nt * 4 + kb) * 256 + lane * 4];
        }
    for (int r = 0; r < 16; ++r) {
        int lt = wave + 4 * r;
        FragI ah[4], al[4];
#pragma unroll
        for (int kb = 0; kb < 4; ++kb) {
            ah[kb].v = *(const int4*)&BFhi[lt * 1024 + kb * 256 + lane * 4];
            al[kb].v = *(const int4*)&BFlo[lt * 1024 + kb * 256 + lane * 4];
        }
        f32x4 a0 = {0.f, 0.f, 0.f, 0.f}, a1 = {0.f, 0.f, 0.f, 0.f};
#pragma unroll
        for (int kb = 0; kb < 4; ++kb) {
            MM(ah[kb].s, bh[0][kb].s, a0);
            MM(ah[kb].s, bl[0][kb].s, a0);
            MM(al[kb].s, bh[0][kb].s, a0);
            MM(ah[kb].s, bh[1][kb].s, a1);
            MM(ah[kb].s, bl[1][kb].s, a1);
            MM(al[kb].s, bh[1][kb].s, a1);
        }
        int lrow = lt * 16 + (lane >> 4) * 4;
        int icol = i0 + (lane & 15);
#pragma unroll
        for (int j = 0; j < 4; ++j) {
            base[(size_t)(lrow + j) * EQ + icol]      = a0[j];
            base[(size_t)(lrow + j) * EQ + icol + 16] = a1[j];
        }
    }
}
#undef MM

extern "C" void kernel_launch(void* const* d_in, const int* in_sizes, int n_in,
                              void* d_out, int out_size, void* d_ws, size_t ws_size,
                              hipStream_t stream) {
    const float* q  = (const float*)d_in[0];
    const float* wr = (const float*)d_in[1];
    const float* wi = (const float*)d_in[2];
    float* out = (float*)d_out;
    unsigned* BFhi = (unsigned*)d_ws;           // u32 [0, 65536)
    unsigned* BFlo = BFhi + 65536;              // u32 [65536, 131072)

    hipLaunchKernelGGL(k_trig,   dim3(256), dim3(256), 0, stream, BFhi, BFlo, out);
    hipLaunchKernelGGL(k_dft4,   dim3(512), dim3(512), 0, stream, q, out);
    hipLaunchKernelGGL(k_modes9, dim3(512), dim3(512), 0, stream, wr, wi, out);
    hipLaunchKernelGGL(k_inv3,   dim3(512), dim3(256), 0, stream, BFhi, BFlo, out);
}

// Round 12
// 142.684 us; speedup vs baseline: 1.4822x; 1.4822x over previous
//
#include <hip/hip_runtime.h>
#include <math.h>

// Problem constants
#define LQ 1024
#define EQ 512
#define BQ 32
#define MQ 64

static constexpr int BCHUNK = LQ * EQ;   // 524288 floats per b-slice of d_out
// d_out overlay (per b-slice of 524288 floats), phase by phase:
//  k_trig:   Tm bf16 A-frags in slice0 floats [0, 131072)
//  k_dft4:   reads q + Tm-frags; writes SPLITX bf16 arrays 0..3 (sx_ptr) in
//            slices z=0..7 at [z][262144, 524288)  (disjoint from Tm-frags)
//  k_modes10:Opart[hs][c][i] hs=0..3 at b*BCHUNK + hs*65536  [0,262144)
//  k_inv3:   y[l][i] overwrites slice. Each block reads ONLY its own i-columns
//            of the 4 partials (staged to LDS before any write -> WAR-safe).
//
// NOTE: __launch_bounds__(512, 4) empirically capped VGPRs at 64 on this
// toolchain (rounds 9-11: VGPR_Count=64, ~170MB scratch spill traffic).
// Use plain __launch_bounds__(512) -> compiler picks ~110 VGPR, no spill.

typedef short short8 __attribute__((ext_vector_type(8)));
typedef float f32x4 __attribute__((ext_vector_type(4)));
typedef unsigned short ushort_t;

union FragI { int i[4]; int4 v; short8 s; };

// async global->LDS, 16B per lane; dest must be wave-uniform base (+lane*16 HW)
__device__ __forceinline__ void gload16(const float* g, float* l) {
    __builtin_amdgcn_global_load_lds(
        (const __attribute__((address_space(1))) void*)g,
        (__attribute__((address_space(3))) void*)l, 16, 0, 0);
}

// SPLITX: 4 bf16 arrays [m(64)][hblk(16)][b(32)][hh(32)], arr: 0=xrHi 1=xrLo
// 2=xiHi 3=xiLo. Flat bf16 index G = arr*2^20 + m*16384 + (h/32)*1024 + b*32
// + (h%32), mapped into 1MB-float zones: z = G>>19 at slice z offset 262144.
__device__ inline char* sx_ptr(float* dout, int arr, int m, int b, int h) {
    unsigned G = ((unsigned)arr << 20) + ((unsigned)m << 14) +
                 ((unsigned)(h >> 5) << 10) + ((unsigned)b << 5) + (unsigned)(h & 31);
    unsigned z = G >> 19, w = G & 524287u;
    return (char*)(dout + (size_t)z * BCHUNK + 262144) + (size_t)w * 2;
}

// split two fp32 into packed bf16 pairs (truncation; lo captures the residual)
__device__ inline void split2(float a, float b, unsigned& hi, unsigned& lo) {
    unsigned ua = __float_as_uint(a), ub = __float_as_uint(b);
    unsigned ha = ua & 0xFFFF0000u, hb = ub & 0xFFFF0000u;
    hi = (ua >> 16) | hb;
    float la = a - __uint_as_float(ha);
    float lb = b - __uint_as_float(hb);
    lo = (__float_as_uint(la) >> 16) | (__float_as_uint(lb) & 0xFFFF0000u);
}

__device__ inline void split1(float x, ushort_t& hi, ushort_t& lo) {
    unsigned u = __float_as_uint(x);
    hi = (ushort_t)(u >> 16);
    float r = x - __uint_as_float(u & 0xFFFF0000u);
    lo = (ushort_t)(__float_as_uint(r) >> 16);
}

// ---------------- kernel 0: trig tables (unchanged) ----------------
__global__ __launch_bounds__(256) void k_trig(unsigned* __restrict__ BFhi,
                                              unsigned* __restrict__ BFlo,
                                              float* __restrict__ dout) {
    int idx = blockIdx.x * 256 + threadIdx.x;   // 0..65535 = l*64+m
    int l = idx >> 6, m = idx & 63;
    int tt = (l * m) & (LQ - 1);
    float ang = (float)tt * 6.135923151542565e-03f;  // 2*pi/1024
    float s, c;
    sincosf(ang, &s, &c);
    float coef = (m == 0 ? 1.0f : 2.0f) * (1.0f / (float)LQ);
    float b0 = coef * c;
    float b1 = (m == 0) ? 0.0f : (-2.0f / (float)LQ) * s;
    unsigned hi, lo;
    split2(b0, b1, hi, lo);
    {
        int lt = l >> 4, kb = m >> 4, kgb = (m & 15) >> 2;
        int lane = kgb * 16 + (l & 15);
        int u = lt * 1024 + kb * 256 + lane * 4 + (m & 3);
        BFhi[u] = hi;
        BFlo[u] = lo;
    }
    ushort_t* THs = (ushort_t*)dout;
    ushort_t* TLs = (ushort_t*)(dout + 65536);
    int ks = l >> 5, kg = (l >> 3) & 3, j = l & 7;
    int mt = m >> 3;
    int lane0 = kg * 16 + 2 * (m & 7);
    ushort_t ch, cl, sh, sl;
    split1(c, ch, cl);
    split1(-s, sh, sl);
    int u0 = ((ks * 8 + mt) * 64 + lane0) * 8 + j;
    THs[u0] = ch;  TLs[u0] = cl;
    THs[u0 + 8] = sh;  TLs[u0 + 8] = sl;
}

#define MM(A, B, C) C = __builtin_amdgcn_mfma_f32_16x16x32_bf16(A, B, C, 0, 0, 0)

// ---------------- kernel 1: truncated DFT via MFMA ----------------
__global__ __launch_bounds__(512) void k_dft4(const float* __restrict__ q,
                                              float* __restrict__ dout) {
    __shared__ float qs[2 * 2048];      // 16KB: [buf][lp 64][h 32]
    const int t    = threadIdx.x;
    const int wave = t >> 6;
    const int lane = t & 63;
    const int a    = wave & 3;
    const int ht   = wave >> 2;
    const int b    = blockIdx.x >> 4;
    const int hg   = blockIdx.x & 15;
    const int hbase = hg * 32;
    const int col  = lane & 15;
    const int kg   = lane >> 4;
    const float* qb = q + (size_t)b * BCHUNK;
    const int4* TH4 = (const int4*)dout;
    const int4* TL4 = (const int4*)(dout + 65536);

    f32x4 acc[2] = {{0.f, 0.f, 0.f, 0.f}, {0.f, 0.f, 0.f, 0.f}};
    const int lp = wave * 8 + (lane >> 3);     // slot row for gload src
    const int hq = 4 * (lane & 7);

    gload16(qb + (size_t)lp * EQ + hbase + hq, &qs[wave * 256]);

    int cur = 0;
    for (int cc = 0; cc < 16; ++cc) {
        __syncthreads();                        // q(cc) ready in buf[cur]
        FragI ah[2][2], al[2][2];
#pragma unroll
        for (int ksl = 0; ksl < 2; ++ksl)
#pragma unroll
            for (int ti = 0; ti < 2; ++ti) {
                int idx = ((cc * 2 + ksl) * 8 + 2 * a + ti) * 64 + lane;
                ah[ksl][ti].v = TH4[idx];
                al[ksl][ti].v = TL4[idx];
            }
        if (cc < 15)
            gload16(qb + (size_t)((cc + 1) * 64 + lp) * EQ + hbase + hq,
                    &qs[(cur ^ 1) * 2048 + wave * 256]);
#pragma unroll
        for (int ksl = 0; ksl < 2; ++ksl) {
            float v[8];
#pragma unroll
            for (int j = 0; j < 8; ++j)
                v[j] = qs[cur * 2048 + (ksl * 32 + kg * 8 + j) * 32 + ht * 16 + col];
            FragI bhiF, bloF;
#pragma unroll
            for (int k2 = 0; k2 < 4; ++k2) {
                unsigned h_, l_;
                split2(v[2 * k2], v[2 * k2 + 1], h_, l_);
                bhiF.i[k2] = (int)h_;
                bloF.i[k2] = (int)l_;
            }
#pragma unroll
            for (int ti = 0; ti < 2; ++ti) {
                MM(ah[ksl][ti].s, bhiF.s, acc[ti]);
                MM(ah[ksl][ti].s, bloF.s, acc[ti]);
                MM(al[ksl][ti].s, bhiF.s, acc[ti]);
            }
        }
        cur ^= 1;
    }
    const int h = hbase + ht * 16 + col;
#pragma unroll
    for (int ti = 0; ti < 2; ++ti) {
        int mt = 2 * a + ti;
        int mA = mt * 8 + kg * 2;
#pragma unroll
        for (int mi = 0; mi < 2; ++mi) {
            float xr = acc[ti][2 * mi];
            float xi = acc[ti][2 * mi + 1];
            ushort_t rh, rl, ih_, il_;
            split1(xr, rh, rl);
            split1(xi, ih_, il_);
            int m = mA + mi;
            *(ushort_t*)sx_ptr(dout, 0, m, b, h) = rh;
            *(ushort_t*)sx_ptr(dout, 1, m, b, h) = rl;
            *(ushort_t*)sx_ptr(dout, 2, m, b, h) = ih_;
            *(ushort_t*)sx_ptr(dout, 3, m, b, h) = il_;
        }
    }
}

// ---------------- kernel 2: per-mode complex GEMM, v11 ----------------
// Opart[hs][b][2m+ri][i] = sum_{h in hs quarter} X[b][h][m] * W[h][i][m]
// grid 512 = hs(4) x mg(16: 4 m) x it(8: 64 i). block 512 = 8 waves.
// Round-11 schedule, de-spilled: peak X liveness 32 regs (xA/xB consumed
// BEFORE xC/xD loaded); xC/xD issued before STAGE so their vmcnt waits
// (<=12) never drain the W prefetch; single vmcnt(0) drain at end barrier.
__global__ __launch_bounds__(512) void k_modes10(const float* __restrict__ wreal,
                                                 const float* __restrict__ wimag,
                                                 float* __restrict__ dout) {
    __shared__ float Wlds[16384];        // 64KB
    const int t    = threadIdx.x;
    const int wave = t >> 6;
    const int lane = t & 63;
    const int isub = wave >> 1;          // 0..3  (16-i subtile)
    const int mw   = wave & 1;           // 0..1  (m-pair)
    const int blk  = blockIdx.x;
    const int hs   = blk >> 7;           // 0..3
    const int mg   = (blk >> 3) & 15;    // 0..15
    const int it   = blk & 7;            // 0..7
    const int i0   = it * 64;
    const int m0   = mg * 4;
    const int col  = lane & 15;
    const int kg   = lane >> 4;
    const int hbase = hs * 128;

    const char* xp0 = sx_ptr(dout, 0, m0 + 2 * mw, col, hbase + kg * 8);

    f32x4 zero4 = {0.f, 0.f, 0.f, 0.f};
    f32x4 acc[2][2][2];                  // [mi][part][nt]
#pragma unroll
    for (int a = 0; a < 2; ++a)
#pragma unroll
        for (int bq = 0; bq < 2; ++bq)
#pragma unroll
            for (int c = 0; c < 2; ++c) acc[a][bq][c] = zero4;

    FragI xA[4], xB[4], xC[4], xD[4];    // xC/xD live only after xA/xB die
    short8 aW[2][2][2];                  // [mi][part][prec]

#define STAGE(KK)                                                             \
    {                                                                         \
        _Pragma("unroll")                                                     \
        for (int r = 0; r < 8; ++r) {                                         \
            const int W64_ = r * 8 + wave;                                    \
            const int part_ = W64_ >> 5;                                      \
            const int h_ = W64_ & 31;                                         \
            const float* src_ = (part_ ? wimag : wreal) +                     \
                (size_t)(hbase + (KK) * 32 + h_) * 32768 +                    \
                (size_t)(i0 + lane) * 64 + m0;                                \
            gload16(src_, &Wlds[W64_ * 256]);                                 \
        }                                                                     \
    }

#define LDX(BUF, MI, NT, KK)                                                  \
    {                                                                         \
        const char* xpm_ = xp0 + (size_t)(MI) * 32768 +                       \
                           (size_t)(KK) * 2048 + (size_t)(NT) * 1024;         \
        BUF[0].v = *(const int4*)(xpm_);                                      \
        BUF[1].v = *(const int4*)(xpm_ + 4194304);                            \
        BUF[2].v = *(const int4*)(xpm_ + 2 * 4194304);                        \
        BUF[3].v = *(const int4*)(xpm_ + 3 * 4194304);                        \
    }

#define MMG(MI, NT, BUF)                                                      \
    {                                                                         \
        FragI th_, tl_, nh_, nl_;                                             \
        th_.s = aW[MI][1][0]; tl_.s = aW[MI][1][1];                           \
        _Pragma("unroll")                                                     \
        for (int k2 = 0; k2 < 4; ++k2) {                                      \
            nh_.i[k2] = th_.i[k2] ^ 0x80008000;                               \
            nl_.i[k2] = tl_.i[k2] ^ 0x80008000;                               \
        }                                                                     \
        MM(aW[MI][0][0], BUF[0].s, acc[MI][0][NT]);                           \
        MM(aW[MI][0][0], BUF[1].s, acc[MI][0][NT]);                           \
        MM(aW[MI][0][1], BUF[0].s, acc[MI][0][NT]);                           \
        MM(nh_.s,        BUF[2].s, acc[MI][0][NT]);                           \
        MM(nh_.s,        BUF[3].s, acc[MI][0][NT]);                           \
        MM(nl_.s,        BUF[2].s, acc[MI][0][NT]);                           \
        MM(aW[MI][0][0], BUF[2].s, acc[MI][1][NT]);                           \
        MM(aW[MI][0][0], BUF[3].s, acc[MI][1][NT]);                           \
        MM(aW[MI][0][1], BUF[2].s, acc[MI][1][NT]);                           \
        MM(aW[MI][1][0], BUF[0].s, acc[MI][1][NT]);                           \
        MM(aW[MI][1][0], BUF[1].s, acc[MI][1][NT]);                           \
        MM(aW[MI][1][1], BUF[0].s, acc[MI][1][NT]);                           \
    }

    // prologue: W chunk 0 + X groups (mi=0) for chunk 0, one drain
    STAGE(0);
    LDX(xA, 0, 0, 0);
    LDX(xB, 0, 1, 0);
    __syncthreads();                     // drain: Wlds(0) + xA/xB ready
    for (int kk = 0; kk < 4; ++kk) {
        // READW both mi: Wlds -> aW registers (LDS reads only)
#pragma unroll
        for (int part = 0; part < 2; ++part) {
            float2 v2[8];
#pragma unroll
            for (int j = 0; j < 8; ++j)
                v2[j] = *(const float2*)&Wlds[(part * 32 + kg * 8 + j) * 256 +
                                              (isub * 16 + col) * 4 + 2 * mw];
#pragma unroll
            for (int mi = 0; mi < 2; ++mi) {
                FragI hiF, loF;
#pragma unroll
                for (int k2 = 0; k2 < 4; ++k2) {
                    float a_ = mi ? v2[2 * k2].y : v2[2 * k2].x;
                    float b_ = mi ? v2[2 * k2 + 1].y : v2[2 * k2 + 1].x;
                    unsigned h_, l_;
                    split2(a_, b_, h_, l_);
                    hiF.i[k2] = (int)h_;
                    loF.i[k2] = (int)l_;
                }
                aW[mi][part][0] = hiF.s;
                aW[mi][part][1] = loF.s;
            }
        }
        __syncthreads();                 // all waves done reading Wlds(kk)
        MMG(0, 0, xA);                   // wait-free (drained at loop entry)
        MMG(0, 1, xB);                   // xA/xB now dead -> regs reusable
        LDX(xC, 1, 0, kk);               // issued BEFORE W prefetch ->
        LDX(xD, 1, 1, kk);               //   waits below keep W in flight
        if (kk < 3) STAGE(kk + 1);       // W prefetch (in flight to barrier)
        MMG(1, 0, xC);                   // vmcnt<=12: xD+W outstanding
        MMG(1, 1, xD);                   // vmcnt<=8: W outstanding
        if (kk < 3) {
            LDX(xA, 0, 0, kk + 1);       // consumed only after drain below
            LDX(xB, 0, 1, kk + 1);
        }
        __syncthreads();                 // single drain: Wlds(kk+1)+xA/xB
    }
#undef STAGE
#undef LDX
#undef MMG
    // epilogue: D row = i = i0 + isub*16 + kg*4 + reg (contig float4), col = b
#pragma unroll
    for (int mi = 0; mi < 2; ++mi)
#pragma unroll
        for (int part = 0; part < 2; ++part)
#pragma unroll
            for (int nt = 0; nt < 2; ++nt) {
                int bb = nt * 16 + col;
                int c = 2 * (m0 + 2 * mw + mi) + part;
                f32x4 vv = acc[mi][part][nt];
                float4 o = make_float4(vv.x, vv.y, vv.z, vv.w);
                *(float4*)&dout[(size_t)bb * BCHUNK + (size_t)hs * 65536 +
                                (size_t)c * EQ + i0 + isub * 16 + kg * 4] = o;
            }
}

// ---------------- kernel 3: truncated irfft via MFMA (unchanged) ----------
__global__ __launch_bounds__(256) void k_inv3(const unsigned* __restrict__ BFhi,
                                              const unsigned* __restrict__ BFlo,
                                              float* __restrict__ dout) {
    __shared__ unsigned Bf[4096];   // [hilo(2)][nt(2)][kb(4)][lane(64)][4] 16KB
    const int t    = threadIdx.x;
    const int wave = t >> 6;
    const int lane = t & 63;
    const int b    = blockIdx.x >> 4;
    const int it   = blockIdx.x & 15;
    const int i0   = it * 32;
    float* base = dout + (size_t)b * BCHUNK;

#pragma unroll
    for (int r = 0; r < 8; ++r) {
        int idx = r * 256 + t;               // 2048 = 64 c-pairs x 32 i
        int il = idx & 31, cp = idx >> 5;
        int c0 = 2 * cp;
        const float* p0 = base + (size_t)c0 * EQ + i0 + il;
        float s0 = p0[0] + p0[65536] + p0[2 * 65536] + p0[3 * 65536];
        const float* p1 = p0 + EQ;
        float s1 = p1[0] + p1[65536] + p1[2 * 65536] + p1[3 * 65536];
        unsigned hi, lo;
        split2(s0, s1, hi, lo);
        int nt = il >> 4, i_loc = il & 15;
        int kb = c0 >> 5, kg = (c0 & 31) >> 3, jp = (c0 & 7) >> 1;
        int u = (nt * 4 + kb) * 256 + (kg * 16 + i_loc) * 4 + jp;
        Bf[u] = hi;
        Bf[2048 + u] = lo;
    }
    __syncthreads();
    FragI bh[2][4], bl[2][4];
#pragma unroll
    for (int nt = 0; nt < 2; ++nt)
#pragma unroll
        for (int kb = 0; kb < 4; ++kb) {
            bh[nt][kb].v = *(const int4*)&Bf[(nt * 4 + kb) * 256 + lane * 4];
            bl[nt][kb].v = *(const int4*)&Bf[2048 + (nt * 4 + kb) * 256 + lane * 4];
        }
    for (int r = 0; r < 16; ++r) {
        int lt = wave + 4 * r;
        FragI ah[4], al[4];
#pragma unroll
        for (int kb = 0; kb < 4; ++kb) {
            ah[kb].v = *(const int4*)&BFhi[lt * 1024 + kb * 256 + lane * 4];
            al[kb].v = *(const int4*)&BFlo[lt * 1024 + kb * 256 + lane * 4];
        }
        f32x4 a0 = {0.f, 0.f, 0.f, 0.f}, a1 = {0.f, 0.f, 0.f, 0.f};
#pragma unroll
        for (int kb = 0; kb < 4; ++kb) {
            MM(ah[kb].s, bh[0][kb].s, a0);
            MM(ah[kb].s, bl[0][kb].s, a0);
            MM(al[kb].s, bh[0][kb].s, a0);
            MM(ah[kb].s, bh[1][kb].s, a1);
            MM(ah[kb].s, bl[1][kb].s, a1);
            MM(al[kb].s, bh[1][kb].s, a1);
        }
        int lrow = lt * 16 + (lane >> 4) * 4;
        int icol = i0 + (lane & 15);
#pragma unroll
        for (int j = 0; j < 4; ++j) {
            base[(size_t)(lrow + j) * EQ + icol]      = a0[j];
            base[(size_t)(lrow + j) * EQ + icol + 16] = a1[j];
        }
    }
}
#undef MM

extern "C" void kernel_launch(void* const* d_in, const int* in_sizes, int n_in,
                              void* d_out, int out_size, void* d_ws, size_t ws_size,
                              hipStream_t stream) {
    const float* q  = (const float*)d_in[0];
    const float* wr = (const float*)d_in[1];
    const float* wi = (const float*)d_in[2];
    float* out = (float*)d_out;
    unsigned* BFhi = (unsigned*)d_ws;           // u32 [0, 65536)
    unsigned* BFlo = BFhi + 65536;              // u32 [65536, 131072)

    hipLaunchKernelGGL(k_trig,    dim3(256), dim3(256), 0, stream, BFhi, BFlo, out);
    hipLaunchKernelGGL(k_dft4,    dim3(512), dim3(512), 0, stream, q, out);
    hipLaunchKernelGGL(k_modes10, dim3(512), dim3(512), 0, stream, wr, wi, out);
    hipLaunchKernelGGL(k_inv3,    dim3(512), dim3(256), 0, stream, BFhi, BFlo, out);
}

// Round 13
// 127.795 us; speedup vs baseline: 1.6549x; 1.1165x over previous
//
#include <hip/hip_runtime.h>
#include <math.h>

// Problem constants
#define LQ 1024
#define EQ 512
#define BQ 32
#define MQ 64

static constexpr int BCHUNK = LQ * EQ;   // 524288 floats per b-slice of d_out
// d_out overlay (per b-slice of 524288 floats), phase by phase:
//  k_trig:   Tm bf16 A-frags in slice0 floats [0, 131072)
//  k_dft4:   reads q + Tm-frags; writes SPLITX bf16 arrays 0..3 (sx_ptr) in
//            slices z=0..7 at [z][262144, 524288)  (disjoint from Tm-frags)
//  k_modes11:Opart[hs][c][i] hs=0..3 at b*BCHUNK + hs*65536  [0,262144)
//  k_inv3:   y[l][i] overwrites slice. Each block reads ONLY its own i-columns
//            of the 4 partials (staged to LDS before any write -> WAR-safe).
//
// PERF MODEL (rounds 7..12): these kernels are bound by VMEM LINE-REQUESTS
// (~45 64B-line requests/cycle chip-wide ~= 6.9 TB/s of line traffic),
// replay-invariant. So: W must be read with FULL 64B lines (m-tile = 16,
// dense reg-staged float2) and X with dense 1KB wave-groups. The m-tile-4
// gload16 variant (rounds 9-12) inflated W requests 4x -> slower despite
// "better" pipelining. Also: __launch_bounds__(512,4) caps VGPR at 64 ->
// massive scratch spill; use plain __launch_bounds__(512).

typedef short short8 __attribute__((ext_vector_type(8)));
typedef float f32x4 __attribute__((ext_vector_type(4)));
typedef unsigned short ushort_t;

union FragI { int i[4]; int4 v; short8 s; };

// async global->LDS, 16B per lane; dest must be wave-uniform base (+lane*16 HW)
__device__ __forceinline__ void gload16(const float* g, float* l) {
    __builtin_amdgcn_global_load_lds(
        (const __attribute__((address_space(1))) void*)g,
        (__attribute__((address_space(3))) void*)l, 16, 0, 0);
}

// SPLITX: 4 bf16 arrays [m(64)][hblk(16)][b(32)][hh(32)], arr: 0=xrHi 1=xrLo
// 2=xiHi 3=xiLo. Flat bf16 index G = arr*2^20 + m*16384 + (h/32)*1024 + b*32
// + (h%32), mapped into 1MB-float zones: z = G>>19 at slice z offset 262144.
__device__ inline char* sx_ptr(float* dout, int arr, int m, int b, int h) {
    unsigned G = ((unsigned)arr << 20) + ((unsigned)m << 14) +
                 ((unsigned)(h >> 5) << 10) + ((unsigned)b << 5) + (unsigned)(h & 31);
    unsigned z = G >> 19, w = G & 524287u;
    return (char*)(dout + (size_t)z * BCHUNK + 262144) + (size_t)w * 2;
}

// split two fp32 into packed bf16 pairs (truncation; lo captures the residual)
__device__ inline void split2(float a, float b, unsigned& hi, unsigned& lo) {
    unsigned ua = __float_as_uint(a), ub = __float_as_uint(b);
    unsigned ha = ua & 0xFFFF0000u, hb = ub & 0xFFFF0000u;
    hi = (ua >> 16) | hb;
    float la = a - __uint_as_float(ha);
    float lb = b - __uint_as_float(hb);
    lo = (__float_as_uint(la) >> 16) | (__float_as_uint(lb) & 0xFFFF0000u);
}

__device__ inline void split1(float x, ushort_t& hi, ushort_t& lo) {
    unsigned u = __float_as_uint(x);
    hi = (ushort_t)(u >> 16);
    float r = x - __uint_as_float(u & 0xFFFF0000u);
    lo = (ushort_t)(__float_as_uint(r) >> 16);
}

// ---------------- kernel 0: trig tables (unchanged) ----------------
__global__ __launch_bounds__(256) void k_trig(unsigned* __restrict__ BFhi,
                                              unsigned* __restrict__ BFlo,
                                              float* __restrict__ dout) {
    int idx = blockIdx.x * 256 + threadIdx.x;   // 0..65535 = l*64+m
    int l = idx >> 6, m = idx & 63;
    int tt = (l * m) & (LQ - 1);
    float ang = (float)tt * 6.135923151542565e-03f;  // 2*pi/1024
    float s, c;
    sincosf(ang, &s, &c);
    float coef = (m == 0 ? 1.0f : 2.0f) * (1.0f / (float)LQ);
    float b0 = coef * c;
    float b1 = (m == 0) ? 0.0f : (-2.0f / (float)LQ) * s;
    unsigned hi, lo;
    split2(b0, b1, hi, lo);
    {
        int lt = l >> 4, kb = m >> 4, kgb = (m & 15) >> 2;
        int lane = kgb * 16 + (l & 15);
        int u = lt * 1024 + kb * 256 + lane * 4 + (m & 3);
        BFhi[u] = hi;
        BFlo[u] = lo;
    }
    ushort_t* THs = (ushort_t*)dout;
    ushort_t* TLs = (ushort_t*)(dout + 65536);
    int ks = l >> 5, kg = (l >> 3) & 3, j = l & 7;
    int mt = m >> 3;
    int lane0 = kg * 16 + 2 * (m & 7);
    ushort_t ch, cl, sh, sl;
    split1(c, ch, cl);
    split1(-s, sh, sl);
    int u0 = ((ks * 8 + mt) * 64 + lane0) * 8 + j;
    THs[u0] = ch;  TLs[u0] = cl;
    THs[u0 + 8] = sh;  TLs[u0 + 8] = sl;
}

#define MM(A, B, C) C = __builtin_amdgcn_mfma_f32_16x16x32_bf16(A, B, C, 0, 0, 0)

// ---------------- kernel 1: truncated DFT via MFMA (unchanged round-12) ----
__global__ __launch_bounds__(512) void k_dft4(const float* __restrict__ q,
                                              float* __restrict__ dout) {
    __shared__ float qs[2 * 2048];      // 16KB: [buf][lp 64][h 32]
    const int t    = threadIdx.x;
    const int wave = t >> 6;
    const int lane = t & 63;
    const int a    = wave & 3;
    const int ht   = wave >> 2;
    const int b    = blockIdx.x >> 4;
    const int hg   = blockIdx.x & 15;
    const int hbase = hg * 32;
    const int col  = lane & 15;
    const int kg   = lane >> 4;
    const float* qb = q + (size_t)b * BCHUNK;
    const int4* TH4 = (const int4*)dout;
    const int4* TL4 = (const int4*)(dout + 65536);

    f32x4 acc[2] = {{0.f, 0.f, 0.f, 0.f}, {0.f, 0.f, 0.f, 0.f}};
    const int lp = wave * 8 + (lane >> 3);     // slot row for gload src
    const int hq = 4 * (lane & 7);

    gload16(qb + (size_t)lp * EQ + hbase + hq, &qs[wave * 256]);

    int cur = 0;
    for (int cc = 0; cc < 16; ++cc) {
        __syncthreads();                        // q(cc) ready in buf[cur]
        FragI ah[2][2], al[2][2];
#pragma unroll
        for (int ksl = 0; ksl < 2; ++ksl)
#pragma unroll
            for (int ti = 0; ti < 2; ++ti) {
                int idx = ((cc * 2 + ksl) * 8 + 2 * a + ti) * 64 + lane;
                ah[ksl][ti].v = TH4[idx];
                al[ksl][ti].v = TL4[idx];
            }
        if (cc < 15)
            gload16(qb + (size_t)((cc + 1) * 64 + lp) * EQ + hbase + hq,
                    &qs[(cur ^ 1) * 2048 + wave * 256]);
#pragma unroll
        for (int ksl = 0; ksl < 2; ++ksl) {
            float v[8];
#pragma unroll
            for (int j = 0; j < 8; ++j)
                v[j] = qs[cur * 2048 + (ksl * 32 + kg * 8 + j) * 32 + ht * 16 + col];
            FragI bhiF, bloF;
#pragma unroll
            for (int k2 = 0; k2 < 4; ++k2) {
                unsigned h_, l_;
                split2(v[2 * k2], v[2 * k2 + 1], h_, l_);
                bhiF.i[k2] = (int)h_;
                bloF.i[k2] = (int)l_;
            }
#pragma unroll
            for (int ti = 0; ti < 2; ++ti) {
                MM(ah[ksl][ti].s, bhiF.s, acc[ti]);
                MM(ah[ksl][ti].s, bloF.s, acc[ti]);
                MM(al[ksl][ti].s, bhiF.s, acc[ti]);
            }
        }
        cur ^= 1;
    }
    const int h = hbase + ht * 16 + col;
#pragma unroll
    for (int ti = 0; ti < 2; ++ti) {
        int mt = 2 * a + ti;
        int mA = mt * 8 + kg * 2;
#pragma unroll
        for (int mi = 0; mi < 2; ++mi) {
            float xr = acc[ti][2 * mi];
            float xi = acc[ti][2 * mi + 1];
            ushort_t rh, rl, ih_, il_;
            split1(xr, rh, rl);
            split1(xi, ih_, il_);
            int m = mA + mi;
            *(ushort_t*)sx_ptr(dout, 0, m, b, h) = rh;
            *(ushort_t*)sx_ptr(dout, 1, m, b, h) = rl;
            *(ushort_t*)sx_ptr(dout, 2, m, b, h) = ih_;
            *(ushort_t*)sx_ptr(dout, 3, m, b, h) = il_;
        }
    }
}

// ---------------- kernel 2: per-mode complex GEMM, v12 ----------------
// = round-8 k_modes6 (round-7 dense-W structure + 4-array SPLITX + W-side
// negation) with the XCD swizzle REMOVED (it regressed) and Opart relocated
// to hs*65536. W staged as full 64B lines (m-tile 16) via reg double-buffer;
// X read as dense 1KB wave-groups. grid 512 = hs(4) x mc(4:16m) x it(32:16i),
// block 512 = 8 waves (wave w -> m-pair {m0+2w, m0+2w+1}).
__global__ __launch_bounds__(512) void k_modes11(const float* __restrict__ wreal,
                                                 const float* __restrict__ wimag,
                                                 float* __restrict__ dout) {
    __shared__ float Wlds[2 * 32 * 16 * 18];   // 73728 B
    const int t    = threadIdx.x;
    const int wave = t >> 6;
    const int lane = t & 63;
    const int blk  = blockIdx.x;         // no swizzle (r8's swizzle regressed)
    const int hs   = blk >> 7;           // 0..3
    const int mc   = (blk >> 5) & 3;
    const int it   = blk & 31;
    const int i0   = it * 16;
    const int m0   = mc * 16;
    const int col  = lane & 15;          // A row (i) / B col (b)
    const int kg   = lane >> 4;          // k-group
    const int hbase = hs * 128;

    const char* xp0 = sx_ptr(dout, 0, m0 + 2 * wave, col, hbase + kg * 8);

    f32x4 zero4 = {0.f, 0.f, 0.f, 0.f};
    f32x4 acc[2][2][2];                  // [mi][part][nt]
#pragma unroll
    for (int a = 0; a < 2; ++a)
#pragma unroll
        for (int bq = 0; bq < 2; ++bq)
#pragma unroll
            for (int c = 0; c < 2; ++c) acc[a][bq][c] = zero4;

    float2 st[16];                       // staging regs (double-buffer)
#define LOADK(KK)                                                             \
    {                                                                         \
        int h0_ = hbase + (KK) * 32;                                          \
        _Pragma("unroll")                                                     \
        for (int r = 0; r < 16; ++r) {                                        \
            int e = r * 512 + t;                                              \
            int m2 = e & 7, ii = (e >> 3) & 15, hh = (e >> 7) & 31;           \
            const float* src = (e >> 12) ? wimag : wreal;                     \
            st[r] = *(const float2*)&src[(size_t)(h0_ + hh) * 32768 +         \
                                         (size_t)(i0 + ii) * 64 + m0 + 2 * m2]; \
        }                                                                     \
    }

    LOADK(0);
    for (int kk = 0; kk < 4; ++kk) {
#pragma unroll
        for (int r = 0; r < 16; ++r) {
            int e = r * 512 + t;
            int m2 = e & 7, ii = (e >> 3) & 15, hh = (e >> 7) & 31;
            int part = e >> 12;
            *(float2*)&Wlds[(((part * 32 + hh) * 16) + ii) * 18 + 2 * m2] = st[r];
        }
        __syncthreads();
        if (kk < 3) LOADK(kk + 1);       // prefetch next chunk under compute
#pragma unroll
        for (int mi = 0; mi < 2; ++mi) {
            const int mloc = 2 * wave + mi;
            short8 aW[2][2];             // [part][prec]: 0=Wr 1=Wi
            short8 nW[2];                // negated Wi hi/lo (exact sign flip)
#pragma unroll
            for (int part = 0; part < 2; ++part) {
                float v[8];
#pragma unroll
                for (int j = 0; j < 8; ++j)
                    v[j] = Wlds[((part * 32 + kg * 8 + j) * 16 + col) * 18 + mloc];
                FragI hiF, loF;
#pragma unroll
                for (int k = 0; k < 4; ++k) {
                    unsigned h, l;
                    split2(v[2 * k], v[2 * k + 1], h, l);
                    hiF.i[k] = (int)h;
                    loF.i[k] = (int)l;
                }
                aW[part][0] = hiF.s;
                aW[part][1] = loF.s;
                if (part == 1) {
                    FragI nh, nl;
#pragma unroll
                    for (int k = 0; k < 4; ++k) {
                        nh.i[k] = hiF.i[k] ^ 0x80008000;
                        nl.i[k] = loF.i[k] ^ 0x80008000;
                    }
                    nW[0] = nh.s;
                    nW[1] = nl.s;
                }
            }
            const char* xpm = xp0 + (size_t)mi * 32768 + (size_t)kk * 2048;
#pragma unroll
            for (int nt = 0; nt < 2; ++nt) {
                short8 bX[4];
#pragma unroll
                for (int arr = 0; arr < 4; ++arr) {
                    FragI f;
                    f.v = *(const int4*)(xpm + (size_t)arr * 4194304 +
                                         (size_t)nt * 1024);
                    bX[arr] = f.s;
                }
                // out_r = Wr*xr + (-Wi)*xi   (3-term split each)
                MM(aW[0][0], bX[0], acc[mi][0][nt]);
                MM(aW[0][0], bX[1], acc[mi][0][nt]);
                MM(aW[0][1], bX[0], acc[mi][0][nt]);
                MM(nW[0],    bX[2], acc[mi][0][nt]);
                MM(nW[0],    bX[3], acc[mi][0][nt]);
                MM(nW[1],    bX[2], acc[mi][0][nt]);
                // out_i = Wr*xi + Wi*xr
                MM(aW[0][0], bX[2], acc[mi][1][nt]);
                MM(aW[0][0], bX[3], acc[mi][1][nt]);
                MM(aW[0][1], bX[2], acc[mi][1][nt]);
                MM(aW[1][0], bX[0], acc[mi][1][nt]);
                MM(aW[1][0], bX[1], acc[mi][1][nt]);
                MM(aW[1][1], bX[0], acc[mi][1][nt]);
            }
        }
        __syncthreads();
    }
#undef LOADK
    // epilogue: D row = i = i0 + kg*4 + reg (contig float4), col = b
#pragma unroll
    for (int mi = 0; mi < 2; ++mi)
#pragma unroll
        for (int part = 0; part < 2; ++part)
#pragma unroll
            for (int nt = 0; nt < 2; ++nt) {
                int bb = nt * 16 + col;
                int c = 2 * (m0 + 2 * wave + mi) + part;
                f32x4 vv = acc[mi][part][nt];
                float4 o = make_float4(vv.x, vv.y, vv.z, vv.w);
                *(float4*)&dout[(size_t)bb * BCHUNK + (size_t)hs * 65536 +
                                (size_t)c * EQ + i0 + kg * 4] = o;
            }
}

// ---------------- kernel 3: truncated irfft via MFMA (unchanged) ----------
__global__ __launch_bounds__(256) void k_inv3(const unsigned* __restrict__ BFhi,
                                              const unsigned* __restrict__ BFlo,
                                              float* __restrict__ dout) {
    __shared__ unsigned Bf[4096];   // [hilo(2)][nt(2)][kb(4)][lane(64)][4] 16KB
    const int t    = threadIdx.x;
    const int wave = t >> 6;
    const int lane = t & 63;
    const int b    = blockIdx.x >> 4;
    const int it   = blockIdx.x & 15;
    const int i0   = it * 32;
    float* base = dout + (size_t)b * BCHUNK;

#pragma unroll
    for (int r = 0; r < 8; ++r) {
        int idx = r * 256 + t;               // 2048 = 64 c-pairs x 32 i
        int il = idx & 31, cp = idx >> 5;
        int c0 = 2 * cp;
        const float* p0 = base + (size_t)c0 * EQ + i0 + il;
        float s0 = p0[0] + p0[65536] + p0[2 * 65536] + p0[3 * 65536];
        const float* p1 = p0 + EQ;
        float s1 = p1[0] + p1[65536] + p1[2 * 65536] + p1[3 * 65536];
        unsigned hi, lo;
        split2(s0, s1, hi, lo);
        int nt = il >> 4, i_loc = il & 15;
        int kb = c0 >> 5, kg = (c0 & 31) >> 3, jp = (c0 & 7) >> 1;
        int u = (nt * 4 + kb) * 256 + (kg * 16 + i_loc) * 4 + jp;
        Bf[u] = hi;
        Bf[2048 + u] = lo;
    }
    __syncthreads();
    FragI bh[2][4], bl[2][4];
#pragma unroll
    for (int nt = 0; nt < 2; ++nt)
#pragma unroll
        for (int kb = 0; kb < 4; ++kb) {
            bh[nt][kb].v = *(const int4*)&Bf[(nt * 4 + kb) * 256 + lane * 4];
            bl[nt][kb].v = *(const int4*)&Bf[2048 + (nt * 4 + kb) * 256 + lane * 4];
        }
    for (int r = 0; r < 16; ++r) {
        int lt = wave + 4 * r;
        FragI ah[4], al[4];
#pragma unroll
        for (int kb = 0; kb < 4; ++kb) {
            ah[kb].v = *(const int4*)&BFhi[lt * 1024 + kb * 256 + lane * 4];
            al[kb].v = *(const int4*)&BFlo[lt * 1024 + kb * 256 + lane * 4];
        }
        f32x4 a0 = {0.f, 0.f, 0.f, 0.f}, a1 = {0.f, 0.f, 0.f, 0.f};
#pragma unroll
        for (int kb = 0; kb < 4; ++kb) {
            MM(ah[kb].s, bh[0][kb].s, a0);
            MM(ah[kb].s, bl[0][kb].s, a0);
            MM(al[kb].s, bh[0][kb].s, a0);
            MM(ah[kb].s, bh[1][kb].s, a1);
            MM(ah[kb].s, bl[1][kb].s, a1);
            MM(al[kb].s, bh[1][kb].s, a1);
        }
        int lrow = lt * 16 + (lane >> 4) * 4;
        int icol = i0 + (lane & 15);
#pragma unroll
        for (int j = 0; j < 4; ++j) {
            base[(size_t)(lrow + j) * EQ + icol]      = a0[j];
            base[(size_t)(lrow + j) * EQ + icol + 16] = a1[j];
        }
    }
}
#undef MM

extern "C" void kernel_launch(void* const* d_in, const int* in_sizes, int n_in,
                              void* d_out, int out_size, void* d_ws, size_t ws_size,
                              hipStream_t stream) {
    const float* q  = (const float*)d_in[0];
    const float* wr = (const float*)d_in[1];
    const float* wi = (const float*)d_in[2];
    float* out = (float*)d_out;
    unsigned* BFhi = (unsigned*)d_ws;           // u32 [0, 65536)
    unsigned* BFlo = BFhi + 65536;              // u32 [65536, 131072)

    hipLaunchKernelGGL(k_trig,    dim3(256), dim3(256), 0, stream, BFhi, BFlo, out);
    hipLaunchKernelGGL(k_dft4,    dim3(512), dim3(512), 0, stream, q, out);
    hipLaunchKernelGGL(k_modes11, dim3(512), dim3(512), 0, stream, wr, wi, out);
    hipLaunchKernelGGL(k_inv3,    dim3(512), dim3(256), 0, stream, BFhi, BFlo, out);
}